// Round 5
// baseline (10972.321 us; speedup 1.0000x reference)
//
#include <hip/hip_runtime.h>
#include <hip/hip_bf16.h>
#include <stdint.h>

// LSTM: S=1024, B=64, D=1024, H=1024. fp32 in/out, bf16 MFMA internally.
// out = [Yt (S*B*H) | hT (B*H) | cT (B*H)] fp32.
// Recurrence: 64 persistent WGs x 512 thr, Wh in VGPRs, h via agent-scope
// (L2-bypassing) atomics. Per-mhalf split arrive/release barrier (32 arrivals,
// broadcast release). Fast exp-based tanh/sigmoid on the dependent path.

typedef __attribute__((ext_vector_type(8))) short bf16x8;
typedef __attribute__((ext_vector_type(4))) float f32x4;

__device__ __forceinline__ unsigned short f2bf(float f) {
    unsigned u = __builtin_bit_cast(unsigned, f);
    return (unsigned short)((u + 0x7fffu + ((u >> 16) & 1u)) >> 16);
}
__device__ __forceinline__ float fast_sigmoid(float x) {
    return __builtin_amdgcn_rcpf(1.f + __expf(-x));
}
__device__ __forceinline__ float fast_tanh(float x) {
    float xc = fminf(fmaxf(x, -9.f), 9.f);
    float e = __expf(2.f * xc);
    return (e - 1.f) * __builtin_amdgcn_rcpf(e + 1.f);
}

// ---------------- init: bias fusion + state zeroing ----------------
__global__ void init_kernel(const float* __restrict__ iiB, const float* __restrict__ hiB,
                            const float* __restrict__ ifB, const float* __restrict__ hfB,
                            const float* __restrict__ igB, const float* __restrict__ hgB,
                            const float* __restrict__ ioB, const float* __restrict__ hoB,
                            float* __restrict__ bias, unsigned short* __restrict__ hbuf0,
                            float* __restrict__ c_ws, unsigned int* __restrict__ bar) {
    int tid = blockIdx.x * 256 + threadIdx.x;   // grid 64 x 256 = 16384
    if (tid < 128) bar[tid] = 0u;   // arrive at [0],[32]; release at [64],[96]
    if (tid < 4096) {
        int g = tid >> 10, j = tid & 1023;
        const float* ib = (g == 0 ? iiB : g == 1 ? ifB : g == 2 ? igB : ioB);
        const float* hb = (g == 0 ? hiB : g == 1 ? hfB : g == 2 ? hgB : hoB);
        bias[tid] = ib[j] + hb[j];
    }
    for (int i = tid; i < 65536; i += 16384) {
        __hip_atomic_store(hbuf0 + i, (unsigned short)0, __ATOMIC_RELAXED, __HIP_MEMORY_SCOPE_AGENT);
        c_ws[i] = 0.f;
    }
}

// ---------------- weights -> bf16, gate-stacked n = g*1024 + j ----------------
__global__ void prep_weights(const float* __restrict__ iiW, const float* __restrict__ hiW,
                             const float* __restrict__ ifW, const float* __restrict__ hfW,
                             const float* __restrict__ igW, const float* __restrict__ hgW,
                             const float* __restrict__ ioW, const float* __restrict__ hoW,
                             unsigned short* __restrict__ Wx, unsigned short* __restrict__ Wh) {
    int n = blockIdx.x;               // 0..4095
    int g = n >> 10, j = n & 1023;
    const float* wx = (g == 0 ? iiW : g == 1 ? ifW : g == 2 ? igW : ioW) + (size_t)j * 1024;
    const float* wh = (g == 0 ? hiW : g == 1 ? hfW : g == 2 ? hgW : hoW) + (size_t)j * 1024;
    int k = threadIdx.x * 4;
    float4 a = *(const float4*)(wx + k);
    float4 b = *(const float4*)(wh + k);
    ushort4 ra = { f2bf(a.x), f2bf(a.y), f2bf(a.z), f2bf(a.w) };
    ushort4 rb = { f2bf(b.x), f2bf(b.y), f2bf(b.z), f2bf(b.w) };
    *(ushort4*)(Wx + (size_t)n * 1024 + k) = ra;
    *(ushort4*)(Wh + (size_t)n * 1024 + k) = rb;
}

// ---------------- Xproj GEMM: C[M][4096] = A[M][1024] @ Wx^T + bias ----------------
// 128x128 tile, BK=32, 4 waves each 64x64 (4x4 of 16x16x32 bf16 MFMA).
__global__ __launch_bounds__(256, 2) void xproj_gemm(const float* __restrict__ A,
                                                     const unsigned short* __restrict__ Wx,
                                                     const float* __restrict__ bias,
                                                     float* __restrict__ C) {
    __shared__ __align__(16) unsigned short Asm[128 * 32];  // 8KB, XOR-swizzled slots
    __shared__ __align__(16) unsigned short Bsm[128 * 32];  // 8KB
    int tid = threadIdx.x;
    int lane = tid & 63, wv = tid >> 6;
    int l15 = lane & 15, l4 = lane >> 4;
    int wrow = wv >> 1, wcol = wv & 1;
    int bn0 = blockIdx.x * 128, bm0 = blockIdx.y * 128;
    f32x4 acc[4][4] = {};

    for (int kk = 0; kk < 32; ++kk) {
        int k0 = kk * 32;
        __syncthreads();   // protect LDS from previous iteration's reads
        // stage A (fp32 -> bf16, swizzled ds_write): 512 tasks of 8 elems
#pragma unroll
        for (int it = 0; it < 2; ++it) {
            int tau = it * 256 + tid;
            int row = tau >> 2, slot = tau & 3;
            const float* src = A + (size_t)(bm0 + row) * 1024 + k0 + slot * 8;
            float4 x0 = *(const float4*)src;
            float4 x1 = *(const float4*)(src + 4);
            bf16x8 pk;
            pk[0] = (short)f2bf(x0.x); pk[1] = (short)f2bf(x0.y);
            pk[2] = (short)f2bf(x0.z); pk[3] = (short)f2bf(x0.w);
            pk[4] = (short)f2bf(x1.x); pk[5] = (short)f2bf(x1.y);
            pk[6] = (short)f2bf(x1.z); pk[7] = (short)f2bf(x1.w);
            int dslot = slot ^ (row & 3);
            *(bf16x8*)((char*)Asm + row * 64 + dslot * 16) = pk;
        }
        // stage B: global_load_lds, linear dest + inverse-swizzled source
#pragma unroll
        for (int it = 0; it < 2; ++it) {
            int tau = it * 256 + tid;
            int row = tau >> 2, slot = tau & 3;
            int sslot = slot ^ (row & 3);
            const unsigned short* src = Wx + (size_t)(bn0 + row) * 1024 + k0 + sslot * 8;
            char* ldsb = (char*)Bsm + it * 4096 + wv * 1024;   // wave-uniform base
            __builtin_amdgcn_global_load_lds((const __attribute__((address_space(1))) void*)src,
                                             (__attribute__((address_space(3))) void*)ldsb, 16, 0, 0);
        }
        __syncthreads();
        bf16x8 af[4], bfv[4];
#pragma unroll
        for (int i = 0; i < 4; ++i) {
            int rowa = wrow * 64 + i * 16 + l15;
            int sa = l4 ^ (rowa & 3);
            af[i] = *(const bf16x8*)((const char*)Asm + rowa * 64 + sa * 16);
            int rowb = wcol * 64 + i * 16 + l15;
            int sb = l4 ^ (rowb & 3);
            bfv[i] = *(const bf16x8*)((const char*)Bsm + rowb * 64 + sb * 16);
        }
#pragma unroll
        for (int i = 0; i < 4; ++i)
#pragma unroll
            for (int j = 0; j < 4; ++j)
                acc[i][j] = __builtin_amdgcn_mfma_f32_16x16x32_bf16(af[i], bfv[j], acc[i][j], 0, 0, 0);
    }
    // epilogue: C = acc + bias[n]
#pragma unroll
    for (int i = 0; i < 4; ++i) {
        int m = bm0 + wrow * 64 + i * 16 + l4 * 4;
#pragma unroll
        for (int j = 0; j < 4; ++j) {
            int n = bn0 + wcol * 64 + j * 16 + l15;
            float bs = bias[n];
#pragma unroll
            for (int r = 0; r < 4; ++r)
                C[(size_t)(m + r) * 4096 + n] = acc[i][j][r] + bs;
        }
    }
}

// ---------------- persistent recurrent kernel (one chunk of T steps) ----------------
// 64 WGs x 512 thr. WG (cgrp, mhalf): 32 hidden units (2 subgroups x 16), all
// 4 gates, batch rows mhalf*32..+32. Wave wv: sg=wv>>2 (j-subgroup), kw=wv&3
// (K-slice of 256). Weights in VGPRs. Barrier: 32 arrive RMWs + broadcast
// release flag, per mhalf.
__global__ __launch_bounds__(512, 1) void lstm_steps(const float* __restrict__ xproj,
                                                     unsigned short* __restrict__ hbuf,
                                                     float* __restrict__ c_ws,
                                                     const unsigned short* __restrict__ Wh,
                                                     unsigned int* __restrict__ bar,
                                                     float* __restrict__ out,
                                                     int t0, int T) {
    __shared__ float red[16384];   // 64KB: [wv:8][32][64]
    int tid = threadIdx.x, lane = tid & 63, wv = tid >> 6;   // wv 0..7
    int l15 = lane & 15, l4 = lane >> 4;
    int wg = blockIdx.x;            // 0..63
    int mhalf = wg & 1;
    int cgrp = wg >> 1;             // 0..31
    int sg = wv >> 2, kw = wv & 3;
    int j0 = cgrp * 32 + sg * 16;
    unsigned int* arrive  = bar + mhalf * 32;        // 128B apart
    unsigned int* release = bar + 64 + mhalf * 32;
    bool leader = (cgrp == 0);

    // this wave's weight fragments: K slice [kw*256, +256), 4 gates x 16 units
    bf16x8 w[8][4];
#pragma unroll
    for (int ks = 0; ks < 8; ++ks)
#pragma unroll
        for (int g = 0; g < 4; ++g) {
            int n = g * 1024 + j0 + l15;
            int k = kw * 256 + ks * 32 + l4 * 8;
            w[ks][g] = *(const bf16x8*)(Wh + (size_t)n * 1024 + k);
        }

    // persistent c state: pairs p = 2*kw + pi, (m = p>>2, r = p&3)
    float c_reg[2];
#pragma unroll
    for (int pi = 0; pi < 2; ++pi) {
        int p = kw * 2 + pi, m = p >> 2, r = p & 3;
        int b = mhalf * 32 + m * 16 + l4 * 4 + r;
        c_reg[pi] = c_ws[(size_t)b * 1024 + j0 + l15];
    }

    for (int tl = 0; tl < T; ++tl) {
        int ts = t0 + tl;
        int par = ts & 1;
        const unsigned short* hb = hbuf + (size_t)par * 65536;

        // ---- xproj prefetch (independent of h; overlaps h load + MFMA) ----
        float xp[2][4];
#pragma unroll
        for (int pi = 0; pi < 2; ++pi) {
            int p = kw * 2 + pi, m = p >> 2, r = p & 3;
            int b = mhalf * 32 + m * 16 + l4 * 4 + r;
#pragma unroll
            for (int g = 0; g < 4; ++g)
                xp[pi][g] = xproj[(size_t)(tl * 64 + b) * 4096 + g * 1024 + j0 + l15];
        }

        // ---- h fragments straight from global (agent loads bypass stale L2) ----
        bf16x8 af[2][8];
#pragma unroll
        for (int m = 0; m < 2; ++m) {
            int row = mhalf * 32 + m * 16 + l15;
            const unsigned short* rp = hb + (size_t)row * 1024 + kw * 256 + l4 * 8;
#pragma unroll
            for (int ks = 0; ks < 8; ++ks) {
                unsigned long long* p = (unsigned long long*)(rp + ks * 32);
                union { unsigned long long q[2]; bf16x8 v; } u;
                u.q[0] = __hip_atomic_load(p,     __ATOMIC_RELAXED, __HIP_MEMORY_SCOPE_AGENT);
                u.q[1] = __hip_atomic_load(p + 1, __ATOMIC_RELAXED, __HIP_MEMORY_SCOPE_AGENT);
                af[m][ks] = u.v;
            }
        }

        f32x4 acc[2][4] = {};
#pragma unroll
        for (int ks = 0; ks < 8; ++ks)
#pragma unroll
            for (int m = 0; m < 2; ++m)
#pragma unroll
                for (int g = 0; g < 4; ++g)
                    acc[m][g] = __builtin_amdgcn_mfma_f32_16x16x32_bf16(af[m][ks], w[ks][g], acc[m][g], 0, 0, 0);

        // cross-wave K reduction in LDS
#pragma unroll
        for (int m = 0; m < 2; ++m)
#pragma unroll
            for (int g = 0; g < 4; ++g)
#pragma unroll
                for (int r = 0; r < 4; ++r)
                    red[(wv * 32 + m * 16 + g * 4 + r) * 64 + lane] = acc[m][g][r];
        __syncthreads();

        // pointwise: wave (sg,kw) handles its subgroup's pairs 2kw, 2kw+1
        float yv[2];
#pragma unroll
        for (int pi = 0; pi < 2; ++pi) {
            int p = kw * 2 + pi, m = p >> 2, r = p & 3;
            int b = mhalf * 32 + m * 16 + l4 * 4 + r;
            int j = j0 + l15;
            float pre[4];
#pragma unroll
            for (int g = 0; g < 4; ++g) {
                int ss = m * 16 + g * 4 + r;
                pre[g] = red[((sg * 4 + 0) * 32 + ss) * 64 + lane] +
                         red[((sg * 4 + 1) * 32 + ss) * 64 + lane] +
                         red[((sg * 4 + 2) * 32 + ss) * 64 + lane] +
                         red[((sg * 4 + 3) * 32 + ss) * 64 + lane] + xp[pi][g];
            }
            float I = fast_sigmoid(pre[0]);
            float F = fast_sigmoid(pre[1]);
            float G = fast_tanh(pre[2]);
            float O = fast_sigmoid(pre[3]);
            float c = F * c_reg[pi] + I * G;
            c_reg[pi] = c;
            float y = O * fast_tanh(c);
            yv[pi] = y;
            __hip_atomic_store(hbuf + (size_t)(par ^ 1) * 65536 + (size_t)b * 1024 + j,
                               f2bf(y), __ATOMIC_RELAXED, __HIP_MEMORY_SCOPE_AGENT);
        }

        // grid barrier (per mhalf): arrive counter RMW by each WG's tid0;
        // leader polls arrivals then broadcasts release; others poll release.
        __syncthreads();   // drains this WG's h stores (L3 ack) first
        if (tid == 0) {
            __hip_atomic_fetch_add(arrive, 1u, __ATOMIC_RELAXED, __HIP_MEMORY_SCOPE_AGENT);
            unsigned target = (unsigned)(ts + 1);
            if (leader) {
                while (__hip_atomic_load(arrive, __ATOMIC_RELAXED, __HIP_MEMORY_SCOPE_AGENT) < target * 32u)
                    __builtin_amdgcn_s_sleep(1);
                __hip_atomic_store(release, target, __ATOMIC_RELAXED, __HIP_MEMORY_SCOPE_AGENT);
            } else {
                while (__hip_atomic_load(release, __ATOMIC_RELAXED, __HIP_MEMORY_SCOPE_AGENT) < target)
                    __builtin_amdgcn_s_sleep(1);
            }
        }
        __syncthreads();

        // deferred HBM stores: overlap with next step's h load + MFMA
#pragma unroll
        for (int pi = 0; pi < 2; ++pi) {
            int p = kw * 2 + pi, m = p >> 2, r = p & 3;
            int b = mhalf * 32 + m * 16 + l4 * 4 + r;
            int j = j0 + l15;
            out[(size_t)(ts * 64 + b) * 1024 + j] = yv[pi];
            if (ts == 1023) {
                out[67108864u + (size_t)b * 1024 + j] = yv[pi];             // hT
                out[67108864u + 65536u + (size_t)b * 1024 + j] = c_reg[pi]; // cT
            }
        }
    }
    // persist c across chunk launches
#pragma unroll
    for (int pi = 0; pi < 2; ++pi) {
        int p = kw * 2 + pi, m = p >> 2, r = p & 3;
        int b = mhalf * 32 + m * 16 + l4 * 4 + r;
        c_ws[(size_t)b * 1024 + j0 + l15] = c_reg[pi];
    }
}

extern "C" void kernel_launch(void* const* d_in, const int* in_sizes, int n_in,
                              void* d_out, int out_size, void* d_ws, size_t ws_size,
                              hipStream_t stream) {
    (void)in_sizes; (void)n_in; (void)out_size;
    const float* Xt = (const float*)d_in[0];
    const float* W[8]; for (int i = 0; i < 8; ++i) W[i] = (const float*)d_in[1 + i];
    const float* Bv[8]; for (int i = 0; i < 8; ++i) Bv[i] = (const float*)d_in[9 + i];
    float* out = (float*)d_out;
    uint8_t* ws = (uint8_t*)d_ws;

    unsigned int*  bar   = (unsigned int*)(ws + 0);           // 128 uints
    float*         bias  = (float*)(ws + 512);
    unsigned short* hbuf = (unsigned short*)(ws + 16896);     // [2][64][1024] bf16
    float*         c_ws  = (float*)(ws + 279040);             // [64][1024] fp32
    unsigned short* Wx   = (unsigned short*)(ws + 541184);    // [4096][1024] bf16
    unsigned short* Wh   = (unsigned short*)(ws + 8929792);   // [4096][1024] bf16
    float*         xproj = (float*)(ws + 17318400);           // [T*64][4096] fp32

    size_t avail = ws_size > 17318400 ? ws_size - 17318400 : 0;
    int T = 4;
    for (int t = 1024; t >= 4; t >>= 1)
        if ((size_t)t * 1048576ull <= avail) { T = t; break; }

    init_kernel<<<64, 256, 0, stream>>>(Bv[0], Bv[1], Bv[2], Bv[3], Bv[4], Bv[5], Bv[6], Bv[7],
                                        bias, hbuf, c_ws, bar);
    prep_weights<<<4096, 256, 0, stream>>>(W[0], W[1], W[2], W[3], W[4], W[5], W[6], W[7], Wx, Wh);

    int nch = 1024 / T;
    for (int c = 0; c < nch; ++c) {
        xproj_gemm<<<dim3(32, T / 2), 256, 0, stream>>>(Xt + (size_t)c * T * 65536, Wx, bias, xproj);
        lstm_steps<<<64, 512, 0, stream>>>(xproj, hbuf, c_ws, Wh, bar, out, c * T, T);
    }
}

// Round 6
// 7210.452 us; speedup vs baseline: 1.5217x; 1.5217x over previous
//
#include <hip/hip_runtime.h>
#include <hip/hip_bf16.h>
#include <stdint.h>

// LSTM: S=1024, B=64, D=1024, H=1024. fp32 in/out, bf16 MFMA internally.
// out = [Yt (S*B*H) | hT (B*H) | cT (B*H)] fp32.
// Recurrence: 128 persistent WGs x 256 thr (R4-measured-good), Wh in VGPRs,
// h via agent-scope atomics, single-counter per-mhalf barrier (direct poll).
// xproj stored gate-interleaved (col = j*4+g) so the consumer reads float4s;
// next-step xproj prefetched across the barrier (latency hides under poll).

typedef __attribute__((ext_vector_type(8))) short bf16x8;
typedef __attribute__((ext_vector_type(4))) float f32x4;

__device__ __forceinline__ unsigned short f2bf(float f) {
    unsigned u = __builtin_bit_cast(unsigned, f);
    return (unsigned short)((u + 0x7fffu + ((u >> 16) & 1u)) >> 16);
}
__device__ __forceinline__ float fast_sigmoid(float x) {
    return __builtin_amdgcn_rcpf(1.f + __expf(-x));
}
__device__ __forceinline__ float fast_tanh(float x) {
    float xc = fminf(fmaxf(x, -9.f), 9.f);
    float e = __expf(2.f * xc);
    return (e - 1.f) * __builtin_amdgcn_rcpf(e + 1.f);
}

// ---------------- init: bias fusion + state zeroing ----------------
__global__ void init_kernel(const float* __restrict__ iiB, const float* __restrict__ hiB,
                            const float* __restrict__ ifB, const float* __restrict__ hfB,
                            const float* __restrict__ igB, const float* __restrict__ hgB,
                            const float* __restrict__ ioB, const float* __restrict__ hoB,
                            float* __restrict__ bias, unsigned short* __restrict__ hbuf0,
                            float* __restrict__ c_ws, unsigned int* __restrict__ bar) {
    int tid = blockIdx.x * 256 + threadIdx.x;   // grid 64 x 256 = 16384
    if (tid < 128) bar[tid] = 0u;               // counters at bar[0], bar[32]
    if (tid < 4096) {
        int g = tid >> 10, j = tid & 1023;
        const float* ib = (g == 0 ? iiB : g == 1 ? ifB : g == 2 ? igB : ioB);
        const float* hb = (g == 0 ? hiB : g == 1 ? hfB : g == 2 ? hgB : hoB);
        bias[tid] = ib[j] + hb[j];
    }
    for (int i = tid; i < 65536; i += 16384) {
        __hip_atomic_store(hbuf0 + i, (unsigned short)0, __ATOMIC_RELAXED, __HIP_MEMORY_SCOPE_AGENT);
        c_ws[i] = 0.f;
    }
}

// ---------------- weights -> bf16, gate-stacked n = g*1024 + j ----------------
__global__ void prep_weights(const float* __restrict__ iiW, const float* __restrict__ hiW,
                             const float* __restrict__ ifW, const float* __restrict__ hfW,
                             const float* __restrict__ igW, const float* __restrict__ hgW,
                             const float* __restrict__ ioW, const float* __restrict__ hoW,
                             unsigned short* __restrict__ Wx, unsigned short* __restrict__ Wh) {
    int n = blockIdx.x;               // 0..4095
    int g = n >> 10, j = n & 1023;
    const float* wx = (g == 0 ? iiW : g == 1 ? ifW : g == 2 ? igW : ioW) + (size_t)j * 1024;
    const float* wh = (g == 0 ? hiW : g == 1 ? hfW : g == 2 ? hgW : hoW) + (size_t)j * 1024;
    int k = threadIdx.x * 4;
    float4 a = *(const float4*)(wx + k);
    float4 b = *(const float4*)(wh + k);
    ushort4 ra = { f2bf(a.x), f2bf(a.y), f2bf(a.z), f2bf(a.w) };
    ushort4 rb = { f2bf(b.x), f2bf(b.y), f2bf(b.z), f2bf(b.w) };
    *(ushort4*)(Wx + (size_t)n * 1024 + k) = ra;
    *(ushort4*)(Wh + (size_t)n * 1024 + k) = rb;
}

// ---------------- Xproj GEMM: C[M][.] = A[M][1024] @ Wx^T + bias ----------------
// 128x128 tile, BK=32, 4 waves each 64x64 (4x4 of 16x16x32 bf16 MFMA).
// Output column PERMUTED: value for gate-stacked n (= g*1024+j) lands at
// column j*4+g, so the recurrent consumer reads one float4 per (b,j).
__global__ __launch_bounds__(256, 2) void xproj_gemm(const float* __restrict__ A,
                                                     const unsigned short* __restrict__ Wx,
                                                     const float* __restrict__ bias,
                                                     float* __restrict__ C) {
    __shared__ __align__(16) unsigned short Asm[128 * 32];  // 8KB, XOR-swizzled slots
    __shared__ __align__(16) unsigned short Bsm[128 * 32];  // 8KB
    int tid = threadIdx.x;
    int lane = tid & 63, wv = tid >> 6;
    int l15 = lane & 15, l4 = lane >> 4;
    int wrow = wv >> 1, wcol = wv & 1;
    int bn0 = blockIdx.x * 128, bm0 = blockIdx.y * 128;
    f32x4 acc[4][4] = {};

    for (int kk = 0; kk < 32; ++kk) {
        int k0 = kk * 32;
        __syncthreads();   // protect LDS from previous iteration's reads
        // stage A (fp32 -> bf16, swizzled ds_write): 512 tasks of 8 elems
#pragma unroll
        for (int it = 0; it < 2; ++it) {
            int tau = it * 256 + tid;
            int row = tau >> 2, slot = tau & 3;
            const float* src = A + (size_t)(bm0 + row) * 1024 + k0 + slot * 8;
            float4 x0 = *(const float4*)src;
            float4 x1 = *(const float4*)(src + 4);
            bf16x8 pk;
            pk[0] = (short)f2bf(x0.x); pk[1] = (short)f2bf(x0.y);
            pk[2] = (short)f2bf(x0.z); pk[3] = (short)f2bf(x0.w);
            pk[4] = (short)f2bf(x1.x); pk[5] = (short)f2bf(x1.y);
            pk[6] = (short)f2bf(x1.z); pk[7] = (short)f2bf(x1.w);
            int dslot = slot ^ (row & 3);
            *(bf16x8*)((char*)Asm + row * 64 + dslot * 16) = pk;
        }
        // stage B: global_load_lds, linear dest + inverse-swizzled source
#pragma unroll
        for (int it = 0; it < 2; ++it) {
            int tau = it * 256 + tid;
            int row = tau >> 2, slot = tau & 3;
            int sslot = slot ^ (row & 3);
            const unsigned short* src = Wx + (size_t)(bn0 + row) * 1024 + k0 + sslot * 8;
            char* ldsb = (char*)Bsm + it * 4096 + wv * 1024;   // wave-uniform base
            __builtin_amdgcn_global_load_lds((const __attribute__((address_space(1))) void*)src,
                                             (__attribute__((address_space(3))) void*)ldsb, 16, 0, 0);
        }
        __syncthreads();
        bf16x8 af[4], bfv[4];
#pragma unroll
        for (int i = 0; i < 4; ++i) {
            int rowa = wrow * 64 + i * 16 + l15;
            int sa = l4 ^ (rowa & 3);
            af[i] = *(const bf16x8*)((const char*)Asm + rowa * 64 + sa * 16);
            int rowb = wcol * 64 + i * 16 + l15;
            int sb = l4 ^ (rowb & 3);
            bfv[i] = *(const bf16x8*)((const char*)Bsm + rowb * 64 + sb * 16);
        }
#pragma unroll
        for (int i = 0; i < 4; ++i)
#pragma unroll
            for (int j = 0; j < 4; ++j)
                acc[i][j] = __builtin_amdgcn_mfma_f32_16x16x32_bf16(af[i], bfv[j], acc[i][j], 0, 0, 0);
    }
    // epilogue: C[m][ (n&1023)*4 + (n>>10) ] = acc + bias[n]
#pragma unroll
    for (int i = 0; i < 4; ++i) {
        int m = bm0 + wrow * 64 + i * 16 + l4 * 4;
#pragma unroll
        for (int j = 0; j < 4; ++j) {
            int n = bn0 + wcol * 64 + j * 16 + l15;
            int col = (n & 1023) * 4 + (n >> 10);
            float bs = bias[n];
#pragma unroll
            for (int r = 0; r < 4; ++r)
                C[(size_t)(m + r) * 4096 + col] = acc[i][j][r] + bs;
        }
    }
}

// ---------------- persistent recurrent kernel (one chunk of T steps) ----------------
// 128 WGs x 256 thr (R4 structure). WG (cg, mhalf): hidden units j0=16*cg..+16,
// all 4 gates, batch rows mhalf*32..+32. Waves K-split (256 each); Wh in VGPRs.
// Single-counter per-mhalf barrier, direct poll. xproj read as float4 (gate-
// interleaved layout), next step prefetched across the barrier.
__global__ __launch_bounds__(256, 1) void lstm_steps(const float* __restrict__ xproj,
                                                     unsigned short* __restrict__ hbuf,
                                                     float* __restrict__ c_ws,
                                                     const unsigned short* __restrict__ Wh,
                                                     unsigned int* __restrict__ bar,
                                                     float* __restrict__ out,
                                                     int t0, int T) {
    __shared__ float red[8192];   // 32KB: [wv:4][32][64]
    int tid = threadIdx.x, lane = tid & 63, wv = tid >> 6;
    int l15 = lane & 15, l4 = lane >> 4;
    int wg = blockIdx.x;
    int mhalf = wg & 1;
    int cg = wg >> 1;
    int j0 = cg * 16;
    unsigned int* mybar = bar + mhalf * 32;   // 128B apart -> separate lines

    // this wave's weight fragments: K slice [wv*256, +256), 4 gates x 16 units
    bf16x8 w[8][4];
#pragma unroll
    for (int ks = 0; ks < 8; ++ks)
#pragma unroll
        for (int g = 0; g < 4; ++g) {
            int n = g * 1024 + j0 + l15;
            int k = wv * 256 + ks * 32 + l4 * 8;
            w[ks][g] = *(const bf16x8*)(Wh + (size_t)n * 1024 + k);
        }

    // persistent c state: pairs p = 2*wv + pi, (m = p>>2, r = p&3)
    float c_reg[2];
    int bq[2];   // batch row per pair
#pragma unroll
    for (int pi = 0; pi < 2; ++pi) {
        int p = wv * 2 + pi, m = p >> 2, r = p & 3;
        bq[pi] = mhalf * 32 + m * 16 + l4 * 4 + r;
        c_reg[pi] = c_ws[(size_t)bq[pi] * 1024 + j0 + l15];
    }

    // prologue: prefetch xproj for step 0 (float4: 4 gates of (b, j))
    float4 xp_cur[2];
#pragma unroll
    for (int pi = 0; pi < 2; ++pi)
        xp_cur[pi] = *(const float4*)(xproj + (size_t)bq[pi] * 4096 + (j0 + l15) * 4);

    for (int tl = 0; tl < T; ++tl) {
        int ts = t0 + tl;
        int par = ts & 1;
        const unsigned short* hb = hbuf + (size_t)par * 65536;

        // ---- h fragments straight from global (agent loads bypass stale L2) ----
        bf16x8 af[2][8];
#pragma unroll
        for (int m = 0; m < 2; ++m) {
            int row = mhalf * 32 + m * 16 + l15;
            const unsigned short* rp = hb + (size_t)row * 1024 + wv * 256 + l4 * 8;
#pragma unroll
            for (int ks = 0; ks < 8; ++ks) {
                unsigned long long* p = (unsigned long long*)(rp + ks * 32);
                union { unsigned long long q[2]; bf16x8 v; } u;
                u.q[0] = __hip_atomic_load(p,     __ATOMIC_RELAXED, __HIP_MEMORY_SCOPE_AGENT);
                u.q[1] = __hip_atomic_load(p + 1, __ATOMIC_RELAXED, __HIP_MEMORY_SCOPE_AGENT);
                af[m][ks] = u.v;
            }
        }

        f32x4 acc[2][4] = {};
#pragma unroll
        for (int ks = 0; ks < 8; ++ks)
#pragma unroll
            for (int m = 0; m < 2; ++m)
#pragma unroll
                for (int g = 0; g < 4; ++g)
                    acc[m][g] = __builtin_amdgcn_mfma_f32_16x16x32_bf16(af[m][ks], w[ks][g], acc[m][g], 0, 0, 0);

        // cross-wave K reduction in LDS
#pragma unroll
        for (int m = 0; m < 2; ++m)
#pragma unroll
            for (int g = 0; g < 4; ++g)
#pragma unroll
                for (int r = 0; r < 4; ++r)
                    red[(wv * 32 + m * 16 + g * 4 + r) * 64 + lane] = acc[m][g][r];
        __syncthreads();

        // pointwise: wave wv handles pairs 2wv, 2wv+1
        float yv[2];
#pragma unroll
        for (int pi = 0; pi < 2; ++pi) {
            int p = wv * 2 + pi, m = p >> 2, r = p & 3;
            int b = bq[pi];
            int j = j0 + l15;
            const float* xpf = (const float*)&xp_cur[pi];
            float pre[4];
#pragma unroll
            for (int g = 0; g < 4; ++g) {
                int s = m * 16 + g * 4 + r;
                pre[g] = red[s * 64 + lane] + red[(32 + s) * 64 + lane] +
                         red[(64 + s) * 64 + lane] + red[(96 + s) * 64 + lane] + xpf[g];
            }
            float I = fast_sigmoid(pre[0]);
            float F = fast_sigmoid(pre[1]);
            float G = fast_tanh(pre[2]);
            float O = fast_sigmoid(pre[3]);
            float c = F * c_reg[pi] + I * G;
            c_reg[pi] = c;
            float y = O * fast_tanh(c);
            yv[pi] = y;
            __hip_atomic_store(hbuf + (size_t)(par ^ 1) * 65536 + (size_t)b * 1024 + j,
                               f2bf(y), __ATOMIC_RELAXED, __HIP_MEMORY_SCOPE_AGENT);
        }

        // drain h stores (L3 ack) before signaling arrival
        __syncthreads();

        // prefetch next step's xproj NOW: loads fly while tid0 polls; the
        // closing __syncthreads (which waits for tid0) also drains them.
        int tln = (tl + 1 < T) ? tl + 1 : tl;
        float4 xp_nxt[2];
#pragma unroll
        for (int pi = 0; pi < 2; ++pi)
            xp_nxt[pi] = *(const float4*)(xproj + (size_t)(tln * 64 + bq[pi]) * 4096 + (j0 + l15) * 4);

        if (tid == 0) {
            __hip_atomic_fetch_add(mybar, 1u, __ATOMIC_RELAXED, __HIP_MEMORY_SCOPE_AGENT);
            unsigned target = (unsigned)(ts + 1) * 64u;
            while (__hip_atomic_load(mybar, __ATOMIC_RELAXED, __HIP_MEMORY_SCOPE_AGENT) < target)
                __builtin_amdgcn_s_sleep(1);
        }
        __syncthreads();

        // deferred HBM stores: overlap with next step's h load + MFMA
#pragma unroll
        for (int pi = 0; pi < 2; ++pi) {
            int b = bq[pi];
            int j = j0 + l15;
            out[(size_t)(ts * 64 + b) * 1024 + j] = yv[pi];
            if (ts == 1023) {
                out[67108864u + (size_t)b * 1024 + j] = yv[pi];             // hT
                out[67108864u + 65536u + (size_t)b * 1024 + j] = c_reg[pi]; // cT
            }
        }
        xp_cur[0] = xp_nxt[0];
        xp_cur[1] = xp_nxt[1];
    }
    // persist c across chunk launches
#pragma unroll
    for (int pi = 0; pi < 2; ++pi)
        c_ws[(size_t)bq[pi] * 1024 + j0 + l15] = c_reg[pi];
}

extern "C" void kernel_launch(void* const* d_in, const int* in_sizes, int n_in,
                              void* d_out, int out_size, void* d_ws, size_t ws_size,
                              hipStream_t stream) {
    (void)in_sizes; (void)n_in; (void)out_size;
    const float* Xt = (const float*)d_in[0];
    const float* W[8]; for (int i = 0; i < 8; ++i) W[i] = (const float*)d_in[1 + i];
    const float* Bv[8]; for (int i = 0; i < 8; ++i) Bv[i] = (const float*)d_in[9 + i];
    float* out = (float*)d_out;
    uint8_t* ws = (uint8_t*)d_ws;

    unsigned int*  bar   = (unsigned int*)(ws + 0);           // 128 uints
    float*         bias  = (float*)(ws + 512);
    unsigned short* hbuf = (unsigned short*)(ws + 16896);     // [2][64][1024] bf16
    float*         c_ws  = (float*)(ws + 279040);             // [64][1024] fp32
    unsigned short* Wx   = (unsigned short*)(ws + 541184);    // [4096][1024] bf16
    unsigned short* Wh   = (unsigned short*)(ws + 8929792);   // [4096][1024] bf16
    float*         xproj = (float*)(ws + 17318400);           // [T*64][4096] fp32

    size_t avail = ws_size > 17318400 ? ws_size - 17318400 : 0;
    int T = 4;
    for (int t = 1024; t >= 4; t >>= 1)
        if ((size_t)t * 1048576ull <= avail) { T = t; break; }

    init_kernel<<<64, 256, 0, stream>>>(Bv[0], Bv[1], Bv[2], Bv[3], Bv[4], Bv[5], Bv[6], Bv[7],
                                        bias, hbuf, c_ws, bar);
    prep_weights<<<4096, 256, 0, stream>>>(W[0], W[1], W[2], W[3], W[4], W[5], W[6], W[7], Wx, Wh);

    int nch = 1024 / T;
    for (int c = 0; c < nch; ++c) {
        xproj_gemm<<<dim3(32, T / 2), 256, 0, stream>>>(Xt + (size_t)c * T * 65536, Wx, bias, xproj);
        lstm_steps<<<128, 256, 0, stream>>>(xproj, hbuf, c_ws, Wh, bar, out, c * T, T);
    }
}

// Round 7
// 7184.497 us; speedup vs baseline: 1.5272x; 1.0036x over previous
//
#include <hip/hip_runtime.h>
#include <hip/hip_bf16.h>
#include <stdint.h>

// LSTM: S=1024, B=64, D=1024, H=1024. fp32 in/out, bf16 MFMA internally.
// out = [Yt (S*B*H) | hT (B*H) | cT (B*H)] fp32.
// Recurrence: 128 persistent WGs x 256 thr, Wh pinned in AGPRs (gfx950
// unified RF; MFMA reads A/B from AGPR), h via agent-scope atomics,
// single-counter per-mhalf barrier. xproj gate-interleaved + prefetched.

typedef __attribute__((ext_vector_type(8))) short bf16x8;
typedef __attribute__((ext_vector_type(4))) float f32x4;

__device__ __forceinline__ unsigned short f2bf(float f) {
    unsigned u = __builtin_bit_cast(unsigned, f);
    return (unsigned short)((u + 0x7fffu + ((u >> 16) & 1u)) >> 16);
}
__device__ __forceinline__ float fast_sigmoid(float x) {
    return __builtin_amdgcn_rcpf(1.f + __expf(-x));
}
__device__ __forceinline__ float fast_tanh(float x) {
    float xc = fminf(fmaxf(x, -9.f), 9.f);
    float e = __expf(2.f * xc);
    return (e - 1.f) * __builtin_amdgcn_rcpf(e + 1.f);
}

// ---------------- init: bias fusion + state zeroing ----------------
__global__ void init_kernel(const float* __restrict__ iiB, const float* __restrict__ hiB,
                            const float* __restrict__ ifB, const float* __restrict__ hfB,
                            const float* __restrict__ igB, const float* __restrict__ hgB,
                            const float* __restrict__ ioB, const float* __restrict__ hoB,
                            float* __restrict__ bias, unsigned short* __restrict__ hbuf0,
                            float* __restrict__ c_ws, unsigned int* __restrict__ bar) {
    int tid = blockIdx.x * 256 + threadIdx.x;   // grid 64 x 256 = 16384
    if (tid < 128) bar[tid] = 0u;               // counters at bar[0], bar[32]
    if (tid < 4096) {
        int g = tid >> 10, j = tid & 1023;
        const float* ib = (g == 0 ? iiB : g == 1 ? ifB : g == 2 ? igB : ioB);
        const float* hb = (g == 0 ? hiB : g == 1 ? hfB : g == 2 ? hgB : hoB);
        bias[tid] = ib[j] + hb[j];
    }
    for (int i = tid; i < 65536; i += 16384) {
        __hip_atomic_store(hbuf0 + i, (unsigned short)0, __ATOMIC_RELAXED, __HIP_MEMORY_SCOPE_AGENT);
        c_ws[i] = 0.f;
    }
}

// ---------------- weights -> bf16, gate-stacked n = g*1024 + j ----------------
__global__ void prep_weights(const float* __restrict__ iiW, const float* __restrict__ hiW,
                             const float* __restrict__ ifW, const float* __restrict__ hfW,
                             const float* __restrict__ igW, const float* __restrict__ hgW,
                             const float* __restrict__ ioW, const float* __restrict__ hoW,
                             unsigned short* __restrict__ Wx, unsigned short* __restrict__ Wh) {
    int n = blockIdx.x;               // 0..4095
    int g = n >> 10, j = n & 1023;
    const float* wx = (g == 0 ? iiW : g == 1 ? ifW : g == 2 ? igW : ioW) + (size_t)j * 1024;
    const float* wh = (g == 0 ? hiW : g == 1 ? hfW : g == 2 ? hgW : hoW) + (size_t)j * 1024;
    int k = threadIdx.x * 4;
    float4 a = *(const float4*)(wx + k);
    float4 b = *(const float4*)(wh + k);
    ushort4 ra = { f2bf(a.x), f2bf(a.y), f2bf(a.z), f2bf(a.w) };
    ushort4 rb = { f2bf(b.x), f2bf(b.y), f2bf(b.z), f2bf(b.w) };
    *(ushort4*)(Wx + (size_t)n * 1024 + k) = ra;
    *(ushort4*)(Wh + (size_t)n * 1024 + k) = rb;
}

// ---------------- Xproj GEMM: C[M][.] = A[M][1024] @ Wx^T + bias ----------------
// 128x128 tile, BK=32, 4 waves each 64x64 (4x4 of 16x16x32 bf16 MFMA).
// Output column PERMUTED: value for gate-stacked n (= g*1024+j) lands at
// column j*4+g, so the recurrent consumer reads one float4 per (b,j).
__global__ __launch_bounds__(256, 2) void xproj_gemm(const float* __restrict__ A,
                                                     const unsigned short* __restrict__ Wx,
                                                     const float* __restrict__ bias,
                                                     float* __restrict__ C) {
    __shared__ __align__(16) unsigned short Asm[128 * 32];  // 8KB, XOR-swizzled slots
    __shared__ __align__(16) unsigned short Bsm[128 * 32];  // 8KB
    int tid = threadIdx.x;
    int lane = tid & 63, wv = tid >> 6;
    int l15 = lane & 15, l4 = lane >> 4;
    int wrow = wv >> 1, wcol = wv & 1;
    int bn0 = blockIdx.x * 128, bm0 = blockIdx.y * 128;
    f32x4 acc[4][4] = {};

    for (int kk = 0; kk < 32; ++kk) {
        int k0 = kk * 32;
        __syncthreads();   // protect LDS from previous iteration's reads
        // stage A (fp32 -> bf16, swizzled ds_write): 512 tasks of 8 elems
#pragma unroll
        for (int it = 0; it < 2; ++it) {
            int tau = it * 256 + tid;
            int row = tau >> 2, slot = tau & 3;
            const float* src = A + (size_t)(bm0 + row) * 1024 + k0 + slot * 8;
            float4 x0 = *(const float4*)src;
            float4 x1 = *(const float4*)(src + 4);
            bf16x8 pk;
            pk[0] = (short)f2bf(x0.x); pk[1] = (short)f2bf(x0.y);
            pk[2] = (short)f2bf(x0.z); pk[3] = (short)f2bf(x0.w);
            pk[4] = (short)f2bf(x1.x); pk[5] = (short)f2bf(x1.y);
            pk[6] = (short)f2bf(x1.z); pk[7] = (short)f2bf(x1.w);
            int dslot = slot ^ (row & 3);
            *(bf16x8*)((char*)Asm + row * 64 + dslot * 16) = pk;
        }
        // stage B: global_load_lds, linear dest + inverse-swizzled source
#pragma unroll
        for (int it = 0; it < 2; ++it) {
            int tau = it * 256 + tid;
            int row = tau >> 2, slot = tau & 3;
            int sslot = slot ^ (row & 3);
            const unsigned short* src = Wx + (size_t)(bn0 + row) * 1024 + k0 + sslot * 8;
            char* ldsb = (char*)Bsm + it * 4096 + wv * 1024;   // wave-uniform base
            __builtin_amdgcn_global_load_lds((const __attribute__((address_space(1))) void*)src,
                                             (__attribute__((address_space(3))) void*)ldsb, 16, 0, 0);
        }
        __syncthreads();
        bf16x8 af[4], bfv[4];
#pragma unroll
        for (int i = 0; i < 4; ++i) {
            int rowa = wrow * 64 + i * 16 + l15;
            int sa = l4 ^ (rowa & 3);
            af[i] = *(const bf16x8*)((const char*)Asm + rowa * 64 + sa * 16);
            int rowb = wcol * 64 + i * 16 + l15;
            int sb = l4 ^ (rowb & 3);
            bfv[i] = *(const bf16x8*)((const char*)Bsm + rowb * 64 + sb * 16);
        }
#pragma unroll
        for (int i = 0; i < 4; ++i)
#pragma unroll
            for (int j = 0; j < 4; ++j)
                acc[i][j] = __builtin_amdgcn_mfma_f32_16x16x32_bf16(af[i], bfv[j], acc[i][j], 0, 0, 0);
    }
    // epilogue: C[m][ (n&1023)*4 + (n>>10) ] = acc + bias[n]
#pragma unroll
    for (int i = 0; i < 4; ++i) {
        int m = bm0 + wrow * 64 + i * 16 + l4 * 4;
#pragma unroll
        for (int j = 0; j < 4; ++j) {
            int n = bn0 + wcol * 64 + j * 16 + l15;
            int col = (n & 1023) * 4 + (n >> 10);
            float bs = bias[n];
#pragma unroll
            for (int r = 0; r < 4; ++r)
                C[(size_t)(m + r) * 4096 + col] = acc[i][j][r] + bs;
        }
    }
}

// ---------------- persistent recurrent kernel (one chunk of T steps) ----------------
// 128 WGs x 256 thr. WG (cg, mhalf): hidden units j0=16*cg..+16, all 4 gates,
// batch rows mhalf*32..+32. Waves K-split (256 each); Wh pinned in AGPRs.
__global__ __launch_bounds__(256, 1) void lstm_steps(const float* __restrict__ xproj,
                                                     unsigned short* __restrict__ hbuf,
                                                     float* __restrict__ c_ws,
                                                     const unsigned short* __restrict__ Wh,
                                                     unsigned int* __restrict__ bar,
                                                     float* __restrict__ out,
                                                     int t0, int T) {
    __shared__ float red[8192];   // 32KB: [wv:4][32][64]
    int tid = threadIdx.x, lane = tid & 63, wv = tid >> 6;
    int l15 = lane & 15, l4 = lane >> 4;
    int wg = blockIdx.x;
    int mhalf = wg & 1;
    int cg = wg >> 1;
    int j0 = cg * 16;
    unsigned int* mybar = bar + mhalf * 32;   // 128B apart -> separate lines

    // this wave's weight fragments: K slice [wv*256, +256), 4 gates x 16 units
    bf16x8 w[8][4];
#pragma unroll
    for (int ks = 0; ks < 8; ++ks)
#pragma unroll
        for (int g = 0; g < 4; ++g) {
            int n = g * 1024 + j0 + l15;
            int k = wv * 256 + ks * 32 + l4 * 8;
            w[ks][g] = *(const bf16x8*)(Wh + (size_t)n * 1024 + k);
        }
    // pin the 128 weight regs into AGPRs (gfx950 unified RF; MFMA reads
    // A/B from AGPR) so the VGPR side holds af/acc without spilling w.
#pragma unroll
    for (int ks = 0; ks < 8; ++ks)
#pragma unroll
        for (int g = 0; g < 4; ++g)
            asm volatile("" : "+a"(w[ks][g]));

    // persistent c state: pairs p = 2*wv + pi, (m = p>>2, r = p&3)
    float c_reg[2];
    int bq[2];   // batch row per pair
#pragma unroll
    for (int pi = 0; pi < 2; ++pi) {
        int p = wv * 2 + pi, m = p >> 2, r = p & 3;
        bq[pi] = mhalf * 32 + m * 16 + l4 * 4 + r;
        c_reg[pi] = c_ws[(size_t)bq[pi] * 1024 + j0 + l15];
    }

    // prologue: prefetch xproj for step 0 (float4: 4 gates of (b, j))
    float4 xp_cur[2];
#pragma unroll
    for (int pi = 0; pi < 2; ++pi)
        xp_cur[pi] = *(const float4*)(xproj + (size_t)bq[pi] * 4096 + (j0 + l15) * 4);

    for (int tl = 0; tl < T; ++tl) {
        int ts = t0 + tl;
        int par = ts & 1;
        const unsigned short* hb = hbuf + (size_t)par * 65536;

        // ---- h fragments straight from global (agent loads bypass stale L2) ----
        bf16x8 af[2][8];
#pragma unroll
        for (int m = 0; m < 2; ++m) {
            int row = mhalf * 32 + m * 16 + l15;
            const unsigned short* rp = hb + (size_t)row * 1024 + wv * 256 + l4 * 8;
#pragma unroll
            for (int ks = 0; ks < 8; ++ks) {
                unsigned long long* p = (unsigned long long*)(rp + ks * 32);
                union { unsigned long long q[2]; bf16x8 v; } u;
                u.q[0] = __hip_atomic_load(p,     __ATOMIC_RELAXED, __HIP_MEMORY_SCOPE_AGENT);
                u.q[1] = __hip_atomic_load(p + 1, __ATOMIC_RELAXED, __HIP_MEMORY_SCOPE_AGENT);
                af[m][ks] = u.v;
            }
        }

        f32x4 acc[2][4] = {};
#pragma unroll
        for (int ks = 0; ks < 8; ++ks)
#pragma unroll
            for (int m = 0; m < 2; ++m)
#pragma unroll
                for (int g = 0; g < 4; ++g)
                    acc[m][g] = __builtin_amdgcn_mfma_f32_16x16x32_bf16(af[m][ks], w[ks][g], acc[m][g], 0, 0, 0);

        // cross-wave K reduction in LDS
#pragma unroll
        for (int m = 0; m < 2; ++m)
#pragma unroll
            for (int g = 0; g < 4; ++g)
#pragma unroll
                for (int r = 0; r < 4; ++r)
                    red[(wv * 32 + m * 16 + g * 4 + r) * 64 + lane] = acc[m][g][r];
        __syncthreads();

        // pointwise: wave wv handles pairs 2wv, 2wv+1
        float yv[2];
#pragma unroll
        for (int pi = 0; pi < 2; ++pi) {
            int p = wv * 2 + pi, m = p >> 2, r = p & 3;
            int b = bq[pi];
            int j = j0 + l15;
            const float* xpf = (const float*)&xp_cur[pi];
            float pre[4];
#pragma unroll
            for (int g = 0; g < 4; ++g) {
                int s = m * 16 + g * 4 + r;
                pre[g] = red[s * 64 + lane] + red[(32 + s) * 64 + lane] +
                         red[(64 + s) * 64 + lane] + red[(96 + s) * 64 + lane] + xpf[g];
            }
            float I = fast_sigmoid(pre[0]);
            float F = fast_sigmoid(pre[1]);
            float G = fast_tanh(pre[2]);
            float O = fast_sigmoid(pre[3]);
            float c = F * c_reg[pi] + I * G;
            c_reg[pi] = c;
            float y = O * fast_tanh(c);
            yv[pi] = y;
            __hip_atomic_store(hbuf + (size_t)(par ^ 1) * 65536 + (size_t)b * 1024 + j,
                               f2bf(y), __ATOMIC_RELAXED, __HIP_MEMORY_SCOPE_AGENT);
        }

        // drain h stores (L3 ack) before signaling arrival
        __syncthreads();

        // prefetch next step's xproj NOW: loads fly while tid0 polls; the
        // closing __syncthreads (which waits for tid0) also drains them.
        int tln = (tl + 1 < T) ? tl + 1 : tl;
        float4 xp_nxt[2];
#pragma unroll
        for (int pi = 0; pi < 2; ++pi)
            xp_nxt[pi] = *(const float4*)(xproj + (size_t)(tln * 64 + bq[pi]) * 4096 + (j0 + l15) * 4);

        if (tid == 0) {
            __hip_atomic_fetch_add(mybar, 1u, __ATOMIC_RELAXED, __HIP_MEMORY_SCOPE_AGENT);
            unsigned target = (unsigned)(ts + 1) * 64u;
            while (__hip_atomic_load(mybar, __ATOMIC_RELAXED, __HIP_MEMORY_SCOPE_AGENT) < target)
                __builtin_amdgcn_s_sleep(1);
        }
        __syncthreads();

        // deferred HBM stores: overlap with next step's h load + MFMA
#pragma unroll
        for (int pi = 0; pi < 2; ++pi) {
            int b = bq[pi];
            int j = j0 + l15;
            out[(size_t)(ts * 64 + b) * 1024 + j] = yv[pi];
            if (ts == 1023) {
                out[67108864u + (size_t)b * 1024 + j] = yv[pi];             // hT
                out[67108864u + 65536u + (size_t)b * 1024 + j] = c_reg[pi]; // cT
            }
        }
        xp_cur[0] = xp_nxt[0];
        xp_cur[1] = xp_nxt[1];
    }
    // persist c across chunk launches
#pragma unroll
    for (int pi = 0; pi < 2; ++pi)
        c_ws[(size_t)bq[pi] * 1024 + j0 + l15] = c_reg[pi];
}

extern "C" void kernel_launch(void* const* d_in, const int* in_sizes, int n_in,
                              void* d_out, int out_size, void* d_ws, size_t ws_size,
                              hipStream_t stream) {
    (void)in_sizes; (void)n_in; (void)out_size;
    const float* Xt = (const float*)d_in[0];
    const float* W[8]; for (int i = 0; i < 8; ++i) W[i] = (const float*)d_in[1 + i];
    const float* Bv[8]; for (int i = 0; i < 8; ++i) Bv[i] = (const float*)d_in[9 + i];
    float* out = (float*)d_out;
    uint8_t* ws = (uint8_t*)d_ws;

    unsigned int*  bar   = (unsigned int*)(ws + 0);           // 128 uints
    float*         bias  = (float*)(ws + 512);
    unsigned short* hbuf = (unsigned short*)(ws + 16896);     // [2][64][1024] bf16
    float*         c_ws  = (float*)(ws + 279040);             // [64][1024] fp32
    unsigned short* Wx   = (unsigned short*)(ws + 541184);    // [4096][1024] bf16
    unsigned short* Wh   = (unsigned short*)(ws + 8929792);   // [4096][1024] bf16
    float*         xproj = (float*)(ws + 17318400);           // [T*64][4096] fp32

    size_t avail = ws_size > 17318400 ? ws_size - 17318400 : 0;
    int T = 4;
    for (int t = 1024; t >= 4; t >>= 1)
        if ((size_t)t * 1048576ull <= avail) { T = t; break; }

    init_kernel<<<64, 256, 0, stream>>>(Bv[0], Bv[1], Bv[2], Bv[3], Bv[4], Bv[5], Bv[6], Bv[7],
                                        bias, hbuf, c_ws, bar);
    prep_weights<<<4096, 256, 0, stream>>>(W[0], W[1], W[2], W[3], W[4], W[5], W[6], W[7], Wx, Wh);

    int nch = 1024 / T;
    for (int c = 0; c < nch; ++c) {
        xproj_gemm<<<dim3(32, T / 2), 256, 0, stream>>>(Xt + (size_t)c * T * 65536, Wx, bias, xproj);
        lstm_steps<<<128, 256, 0, stream>>>(xproj, hbuf, c_ws, Wh, bar, out, c * T, T);
    }
}